// Round 5
// baseline (341.250 us; speedup 1.0000x reference)
//
#include <hip/hip_runtime.h>
#include <math.h>

#define G 512
#define N 400
#define D 128
#define K 200
#define DOUT 512
#define DMID 32
#define GK (G*K)      // 102400
#define KD (K*D)      // 25600
#define NCHUNK 200    // GEMM2 k-chunks of 128

#define SH  129       // sHt stride (GEMM2)
#define SW2 36        // padded stride for W2T tile (GEMM2)

#define NT 13         // m-tiles of 32 rows in gemm1_pool (416 slots, 400 valid)
#define TPB 512       // threads per block of gemm1_pool (8 waves)
#define TS  132       // padded fp32 tile stride (132%32=4 -> <=4-way on frag reads)

// dynamic LDS layout for gemm1_pool (bytes):
//   float  s_acc[200][128]    102400
//   float  s_tile[2][32][132]  33792
//   int    s_ids[400]           1600
//   int    s_cnt[200]            800
#define G1_LDS (102400 + 33792 + 1600 + 800)  // 138592

__device__ __forceinline__ float relu(float v) { return fmaxf(v, 0.0f); }

typedef __attribute__((ext_vector_type(8))) short short8b;   // 8 bf16 = 4 VGPR
typedef __attribute__((ext_vector_type(16))) float floatx16; // mfma 32x32 acc

__device__ __forceinline__ ushort f2bf(float f) {  // fp32 -> bf16 (RNE)
  unsigned u = __float_as_uint(f);
  unsigned r = (u + 0x7FFFu + ((u >> 16) & 1u)) >> 16;
  return (ushort)r;
}
__device__ __forceinline__ float bf2f(ushort h) {
  return __uint_as_float(((unsigned)h) << 16);
}

// Native non-returning LDS float add (single DS op, no CAS retry loop).
__device__ __forceinline__ void lds_fadd(float* p, float v) {
  asm volatile("ds_add_f32 %0, %1"
               :
               : "v"((unsigned)(unsigned long long)p), "v"(v)
               : "memory");
}

// ---------------- K1b: W1 -> fragment-major hi/lo bf16 (B-operand prep) ----------------
// layout: wh[nt][ks][l][i] holds W1[k*D + n], k = ks*16 + (l>>5)*8 + i, n = nt*32 + (l&31)
__global__ __launch_bounds__(256) void w1prep(
    const float* __restrict__ W1, ushort* __restrict__ wh, ushort* __restrict__ wl) {
  const int idx = blockIdx.x * 256 + threadIdx.x;  // < 16384
  const int i = idx & 7, l = (idx >> 3) & 63, ks = (idx >> 9) & 7, nt = idx >> 12;
  const int k = ks * 16 + (l >> 5) * 8 + i;
  const int n = nt * 32 + (l & 31);
  const float v = W1[k * D + n];
  const ushort h = f2bf(v);
  wh[idx] = h;
  wl[idx] = f2bf(v - bf2f(h));
}

// ---------------- K1: dense GEMM (x @ W1) then segment-mean pooling ----------------
// One block per g, 8 waves. Key fix vs rounds 1-4: x is loaded COALESCED
// (contiguous lane addressing, 16 cache lines / dwordx4 instr) into a shared
// fp32 LDS tile [32][TS]; the strided frag access (512 B row stride, 32
// lines/instr -> TA/TCP serialization = the ~300 us pathology) now happens in
// LDS, where the padded stride makes it a cheap <=4-way bank alias. Waves read
// A-frags from the tile, convert to split hi/lo bf16 in regs, MFMA, and
// scatter y-fragments into s_acc[cluster][n] via ds_add_f32 (linearity:
// mean(x)@W1 == mean(x@W1)). Double-buffered, regs 2 tiles ahead, 1 barrier
// per tile. Wave w: nt = w&3, ksbase = (w>>2)*4 (K split; partials combine in
// the scatter). Epilogue: 1/cnt, +b1, relu, coalesced float4 store.
__global__ __launch_bounds__(TPB, 1) void gemm1_pool(
    const float* __restrict__ x, const int* __restrict__ cluster,
    const ushort* __restrict__ wh, const ushort* __restrict__ wl,
    const float* __restrict__ b1, float* __restrict__ h1) {
  extern __shared__ char smem[];
  float* s_acc  = (float*)smem;                      // [200][128]
  float* s_tile = (float*)(smem + 102400);           // [2][32][TS]
  int*   s_ids  = (int*)(smem + 102400 + 33792);     // [400]
  int*   s_cnt  = s_ids + 400;                       // [200]

  const int g = blockIdx.x;
  const int tid = threadIdx.x;
  const int lane = tid & 63;
  const int w = tid >> 6;
  const int nt = w & 3, ksbase = (w >> 2) * 4;

  const float* xg = x + (size_t)g * N * D;

  // staging geometry: thread t covers row = t>>4, floats [(t&15)*4, +4) and +64
  const int srow = tid >> 4, sc4 = (tid & 15) * 4;

#define LOADT(MT, R0, R1)                                                   \
  {                                                                         \
    int rr = (MT) * 32 + srow; rr = rr < N ? rr : N - 1;                    \
    const float* p = xg + (size_t)rr * D;                                   \
    R0 = *(const float4*)(p + sc4);                                         \
    R1 = *(const float4*)(p + sc4 + 64);                                    \
  }

#define TWRITE(BUF, R0, R1)                                                 \
  {                                                                         \
    float* tp = s_tile + (BUF) * 32 * TS + srow * TS;                       \
    *(float4*)(tp + sc4) = R0;                                              \
    *(float4*)(tp + sc4 + 64) = R1;                                         \
  }

  // ---- prologue: issue tile 0/1 loads early, zero acc/cnt ----
  float4 RA0, RA1, RB0, RB1;
  LOADT(0, RA0, RA1);
  LOADT(1, RB0, RB1);
  for (int i = tid; i < K * D / 4; i += TPB)
    ((float4*)s_acc)[i] = make_float4(0.f, 0.f, 0.f, 0.f);
  if (tid < K) s_cnt[tid] = 0;
  __syncthreads();  // B1: zeroing visible

  if (tid < N) {
    const int id = cluster[g * N + tid];
    s_ids[tid] = id;
    atomicAdd(&s_cnt[id], 1);
  }
  TWRITE(0, RA0, RA1);  // tile 0 -> buf 0

  // hoist W1 B-frags for this wave (nt, 4 ks) into registers
  short8b Bh[4], Bl[4];
#pragma unroll
  for (int kk = 0; kk < 4; ++kk) {
    const int ks = ksbase + kk;
    Bh[kk] = *(const short8b*)&wh[((nt * 8 + ks) * 64 + lane) * 8];
    Bl[kk] = *(const short8b*)&wl[((nt * 8 + ks) * 64 + lane) * 8];
  }
  __syncthreads();  // B2: ids, counts, tile-0 visible

  const int col = lane & 31;
  const int rbase4 = 4 * (lane >> 5);
  // frag source in tile: row = lane&31, k-offset (lane>>5)*8
  const int frow = lane & 31, fkoff = (lane >> 5) << 3;

  // ---- main loop: 1 barrier/tile; loads 2 tiles ahead, LDS writes 1 ahead ----
  for (int mt = 0; mt < NT; ++mt) {
    const int buf = mt & 1;
    if (mt + 2 < NT) {  // issue loads for tile mt+2 (parity mt&1)
      if (mt & 1) { LOADT(mt + 2, RB0, RB1); } else { LOADT(mt + 2, RA0, RA1); }
    }
    if (mt + 1 < NT) {  // write tile mt+1's fp32 data (loaded 2 iters ago)
      if ((mt + 1) & 1) { TWRITE(1, RB0, RB1); } else { TWRITE(0, RA0, RA1); }
    }

    // gather this tile's 16 cluster ids (broadcast LDS reads, batched)
    const int rowbase = mt * 32 + rbase4;
    int ids[16];
#pragma unroll
    for (int q = 0; q < 4; ++q) {
      const int4 t = *(const int4*)&s_ids[rowbase + 8 * q];
      ids[q * 4 + 0] = t.x; ids[q * 4 + 1] = t.y;
      ids[q * 4 + 2] = t.z; ids[q * 4 + 3] = t.w;
    }

    floatx16 acc;
#pragma unroll
    for (int e = 0; e < 16; ++e) acc[e] = 0.0f;

    const float* tb = s_tile + buf * 32 * TS + frow * TS + fkoff;
#pragma unroll
    for (int kk = 0; kk < 4; ++kk) {
      const int ks = ksbase + kk;
      const float4 f0 = *(const float4*)(tb + ks * 16);
      const float4 f1 = *(const float4*)(tb + ks * 16 + 4);
      float vv[8] = {f0.x, f0.y, f0.z, f0.w, f1.x, f1.y, f1.z, f1.w};
      short8b ah, al;
#pragma unroll
      for (int e = 0; e < 8; ++e) {
        const ushort hh = f2bf(vv[e]);
        ah[e] = (short)hh;
        al[e] = (short)f2bf(vv[e] - bf2f(hh));
      }
      acc = __builtin_amdgcn_mfma_f32_32x32x16_bf16(ah, Bh[kk], acc, 0, 0, 0);
      acc = __builtin_amdgcn_mfma_f32_32x32x16_bf16(ah, Bl[kk], acc, 0, 0, 0);
      acc = __builtin_amdgcn_mfma_f32_32x32x16_bf16(al, Bh[kk], acc, 0, 0, 0);
    }

    // scatter y-fragments into per-cluster accumulator (bank = col: conflict-free)
#pragma unroll
    for (int e = 0; e < 16; ++e) {
      const int r = rowbase + (e & 3) + 8 * (e >> 2);
      if (r < N) lds_fadd(&s_acc[ids[e] * D + nt * 32 + col], acc[e]);
    }
    __syncthreads();
  }
#undef LOADT
#undef TWRITE

  // drain this wave's untracked ds_adds, then one final block sync
  asm volatile("s_waitcnt lgkmcnt(0)" ::: "memory");
  __syncthreads();

  // ---- epilogue: mean + bias + relu, coalesced float4 stores ----
  float* og = h1 + (size_t)g * KD;
  for (int i = tid; i < K * D / 4; i += TPB) {
    const int row = i >> 5;
    const int c = s_cnt[row];
    const float iv = 1.0f / (float)(c > 0 ? c : 1);
    const float4 a = ((const float4*)s_acc)[i];
    const float4 bb = *(const float4*)&b1[(i & 31) * 4];
    float4 o;
    o.x = relu(fmaf(a.x, iv, bb.x));
    o.y = relu(fmaf(a.y, iv, bb.y));
    o.z = relu(fmaf(a.z, iv, bb.z));
    o.w = relu(fmaf(a.w, iv, bb.w));
    ((float4*)og)[i] = o;
  }
}

// ---------------- K3: GEMM2 partials (32-row g-blocks) ----------------
__global__ __launch_bounds__(256) void gemm2_partial(
    const float* __restrict__ h1, const float* __restrict__ W2,
    float* __restrict__ partials) {
  extern __shared__ float smemf[];
  float* sHt = smemf;            // [32][SH]
  float* sWT = smemf + 32 * SH;  // [128][SW2]
  const int kc = blockIdx.x;     // 0..199
  const int gb = blockIdx.y;     // 0..15
  const int k0 = kc * 128, g0 = gb * 32;
  const int tid = threadIdx.x;

  for (int i = tid; i < 32 * 128; i += 256) {
    const int r = i >> 7, k = i & 127;
    sHt[r * SH + k] = h1[(size_t)(g0 + r) * KD + k0 + k];
  }
  for (int i = tid; i < 32 * 128; i += 256) {
    const int j = i >> 7, k = i & 127;
    sWT[k * SW2 + j] = W2[(size_t)j * KD + k0 + k];
  }
  __syncthreads();

  const int jt = tid & 7;   // j block of 4
  const int gt = tid >> 3;  // one g row each (32)
  float acc[4];
#pragma unroll
  for (int j = 0; j < 4; j++) acc[j] = 0.0f;

  for (int k = 0; k < 128; ++k) {
    const float h = sHt[gt * SH + k];
    const float4 w0 = *(const float4*)&sWT[k * SW2 + jt * 4];
    acc[0] = fmaf(h, w0.x, acc[0]); acc[1] = fmaf(h, w0.y, acc[1]);
    acc[2] = fmaf(h, w0.z, acc[2]); acc[3] = fmaf(h, w0.w, acc[3]);
  }

  float* pp = partials + ((size_t)kc * G + g0 + gt) * DMID + jt * 4;
  *(float4*)&pp[0] = make_float4(acc[0], acc[1], acc[2], acc[3]);
}

// ---------------- K4a: reduce stage 1 (200 -> 8), grid (64, 8) ----------------
__global__ __launch_bounds__(256) void gemm2_reduce1(
    const float* __restrict__ partials, float* __restrict__ partials2) {
  const int idx = blockIdx.x * 256 + threadIdx.x;  // < G*DMID
  const int cg = blockIdx.y;                        // 0..7
  float s = 0.0f;
  for (int c = cg * 25; c < cg * 25 + 25; ++c)
    s += partials[(size_t)c * G * DMID + idx];
  partials2[(size_t)cg * G * DMID + idx] = s;
}

// ---------------- K4b: reduce stage 2 (8 -> h2) ----------------
__global__ __launch_bounds__(256) void gemm2_reduce2(
    const float* __restrict__ partials2, const float* __restrict__ b2,
    float* __restrict__ h2) {
  const int idx = blockIdx.x * 256 + threadIdx.x;  // < G*DMID
  const int j = idx & 31;
  float s = 0.0f;
#pragma unroll
  for (int c = 0; c < 8; ++c) s += partials2[(size_t)c * G * DMID + idx];
  h2[idx] = relu(s + b2[j]);
}

// ---------------- K5: GEMM3 + cosine + per-pair squared error ----------------
__global__ __launch_bounds__(256) void head_kernel(
    const float* __restrict__ h2, const float* __restrict__ W3,
    const float* __restrict__ b3, const float* __restrict__ ts,
    float* __restrict__ pair_sq) {
  __shared__ float sA[DMID], sB[DMID];
  __shared__ float rdot[4], rna[4], rnb[4];
  const int p = blockIdx.x;
  const int tid = threadIdx.x;
  if (tid < DMID) sA[tid] = h2[(size_t)(2 * p) * DMID + tid];
  else if (tid < 2 * DMID) sB[tid - DMID] = h2[(size_t)(2 * p + 1) * DMID + (tid - DMID)];
  __syncthreads();

  float dot = 0.0f, na = 0.0f, nb = 0.0f;
#pragma unroll
  for (int rep = 0; rep < 2; ++rep) {
    const int o = rep * 256 + tid;
    const float* w = W3 + (size_t)o * DMID;
    float accA = b3[o], accB = accA;
#pragma unroll
    for (int m = 0; m < DMID; m += 4) {
      const float4 wv = *(const float4*)&w[m];
      accA = fmaf(sA[m], wv.x, accA); accB = fmaf(sB[m], wv.x, accB);
      accA = fmaf(sA[m + 1], wv.y, accA); accB = fmaf(sB[m + 1], wv.y, accB);
      accA = fmaf(sA[m + 2], wv.z, accA); accB = fmaf(sB[m + 2], wv.z, accB);
      accA = fmaf(sA[m + 3], wv.w, accA); accB = fmaf(sB[m + 3], wv.w, accB);
    }
    const float a = relu(accA), b = relu(accB);
    dot = fmaf(a, b, dot); na = fmaf(a, a, na); nb = fmaf(b, b, nb);
  }
#pragma unroll
  for (int off = 32; off >= 1; off >>= 1) {
    dot += __shfl_down(dot, off);
    na  += __shfl_down(na, off);
    nb  += __shfl_down(nb, off);
  }
  const int wave = tid >> 6, lane = tid & 63;
  if (lane == 0) { rdot[wave] = dot; rna[wave] = na; rnb[wave] = nb; }
  __syncthreads();
  if (tid == 0) {
    const float dt = rdot[0] + rdot[1] + rdot[2] + rdot[3];
    const float nA = rna[0] + rna[1] + rna[2] + rna[3];
    const float nB = rnb[0] + rnb[1] + rnb[2] + rnb[3];
    const float n1 = fmaxf(sqrtf(nA), 1e-6f);
    const float n2 = fmaxf(sqrtf(nB), 1e-6f);
    const float sc = dt / (n1 * n2);
    const float e = sc - ts[p];
    pair_sq[p] = e * e;
  }
}

// ---------------- K6: final mean ----------------
__global__ __launch_bounds__(256) void loss_kernel(
    const float* __restrict__ pair_sq, float* __restrict__ out) {
  __shared__ float red[4];
  const int tid = threadIdx.x;
  float v = pair_sq[tid];
#pragma unroll
  for (int off = 32; off >= 1; off >>= 1) v += __shfl_down(v, off);
  const int wave = tid >> 6, lane = tid & 63;
  if (lane == 0) red[wave] = v;
  __syncthreads();
  if (tid == 0) out[0] = (red[0] + red[1] + red[2] + red[3]) * (1.0f / 256.0f);
}

extern "C" void kernel_launch(void* const* d_in, const int* in_sizes, int n_in,
                              void* d_out, int out_size, void* d_ws, size_t ws_size,
                              hipStream_t stream) {
  const float* x       = (const float*)d_in[0];
  const int*   cluster = (const int*)d_in[1];
  const float* ts      = (const float*)d_in[2];
  const float* W1      = (const float*)d_in[3];
  const float* b1      = (const float*)d_in[4];
  const float* W2      = (const float*)d_in[5];
  const float* b2      = (const float*)d_in[6];
  const float* W3      = (const float*)d_in[7];
  const float* b3      = (const float*)d_in[8];

  float* ws = (float*)d_ws;
  float* h1        = ws;                                   // GK*D
  float* partials  = h1 + (size_t)GK * D;                  // NCHUNK*G*DMID
  float* h2        = partials + (size_t)NCHUNK * G * DMID; // G*DMID
  float* pair_sq   = h2 + (size_t)G * DMID;                // 256
  float* partials2 = pair_sq + 256;                        // 8*G*DMID
  ushort* wfrag_hi = (ushort*)(partials2 + 8 * G * DMID);  // 16384 bf16
  ushort* wfrag_lo = wfrag_hi + 16384;                     // 16384 bf16

  // allow >64 KB dynamic LDS for gemm1_pool (host-side attr, graph-capture safe)
  static bool attr_set = false;
  if (!attr_set) {
    (void)hipFuncSetAttribute((const void*)gemm1_pool,
                              hipFuncAttributeMaxDynamicSharedMemorySize,
                              160 * 1024);
    attr_set = true;
  }

  w1prep<<<16384 / 256, 256, 0, stream>>>(W1, wfrag_hi, wfrag_lo);
  gemm1_pool<<<G, TPB, G1_LDS, stream>>>(x, cluster, wfrag_hi, wfrag_lo, b1, h1);
  dim3 gridC(NCHUNK, 16);
  gemm2_partial<<<gridC, 256, (32 * SH + 128 * SW2) * sizeof(float), stream>>>(h1, W2, partials);
  dim3 gridR1(G * DMID / 256, 8);
  gemm2_reduce1<<<gridR1, 256, 0, stream>>>(partials, partials2);
  gemm2_reduce2<<<G * DMID / 256, 256, 0, stream>>>(partials2, b2, h2);
  head_kernel<<<G / 2, 256, 0, stream>>>(h2, W3, b3, ts, pair_sq);
  loss_kernel<<<1, 256, 0, stream>>>(pair_sq, (float*)d_out);
}

// Round 6
// 89.757 us; speedup vs baseline: 3.8019x; 3.8019x over previous
//
#include <hip/hip_runtime.h>
#include <math.h>

#define G 512
#define N 400
#define D 128
#define K 200
#define DOUT 512
#define DMID 32
#define GK (G*K)      // 102400
#define KD (K*D)      // 25600
#define NCHUNK 200    // GEMM2 k-chunks of 128

#define SH  129       // sHt stride (GEMM2)
#define SW2 36        // padded stride for W2T tile (GEMM2)

#define KQ 25         // clusters per fused block (grid (8,G))

__device__ __forceinline__ float relu(float v) { return fmaxf(v, 0.0f); }

typedef __attribute__((ext_vector_type(8))) short short8b;   // 8 bf16 = 4 VGPR
typedef __attribute__((ext_vector_type(16))) float floatx16; // mfma 32x32 acc

__device__ __forceinline__ ushort f2bf(float f) {  // fp32 -> bf16 (RNE)
  unsigned u = __float_as_uint(f);
  unsigned r = (u + 0x7FFFu + ((u >> 16) & 1u)) >> 16;
  return (ushort)r;
}
__device__ __forceinline__ float bf2f(ushort h) {
  return __uint_as_float(((unsigned)h) << 16);
}

// ---------------- K1b: W1 -> fragment-major hi/lo bf16 (B-operand prep) ----------------
__global__ __launch_bounds__(256) void w1prep(
    const float* __restrict__ W1, ushort* __restrict__ wh, ushort* __restrict__ wl) {
  const int idx = blockIdx.x * 256 + threadIdx.x;  // < 16384
  const int i = idx & 7, l = (idx >> 3) & 63, ks = (idx >> 9) & 7, nt = idx >> 12;
  const int k = ks * 16 + (l >> 5) * 8 + i;
  const int n = nt * 32 + (l & 31);
  const float v = W1[k * D + n];
  const ushort h = f2bf(v);
  wh[idx] = h;
  wl[idx] = f2bf(v - bf2f(h));
}

// ---------------- K1: FUSED pool + GEMM1, 25-cluster blocks, 8 blocks/CU ----------------
// Block = (g, 25-cluster octant), grid (8,G)=4096. Phase A: bucket-sort rows,
// gather-mean (batched 8-deep pipelined loads), flush rows as hi/lo bf16 frags
// into ONE 32-row m-tile (XOR-ks swizzle; rows 25..31 pre-zeroed). Scan = one
// wave-0 shfl_up pass. Phase B: 24 MFMAs, scatter epilogue. ~20 KB LDS.
__global__ __launch_bounds__(256) void pool_gemm1_fused(
    const float* __restrict__ x, const int* __restrict__ cluster,
    const ushort* __restrict__ wh, const ushort* __restrict__ wl,
    const float* __restrict__ b1, float* __restrict__ h1) {
  __shared__ int s_ids[N];
  __shared__ int s_cnt[KQ];
  __shared__ int s_off[KQ + 1];
  __shared__ int s_cur[KQ];
  __shared__ int s_sorted[N];           // packed (local_id<<9)|row
  __shared__ ushort sAhi[8 * 64 * 8];   // [ks][slot^ks][i], 8 KB
  __shared__ ushort sAlo[8 * 64 * 8];
  const int g = blockIdx.y;
  const int kb = blockIdx.x * KQ;
  const int tid = threadIdx.x;
  const int* cg = cluster + g * N;

  for (int i = tid; i < N; i += 256) s_ids[i] = cg[i];
  if (tid < KQ) { s_cnt[tid] = 0; s_cur[tid] = 0; }
  {
    short8b z;
#pragma unroll
    for (int e = 0; e < 8; ++e) z[e] = 0;
    for (int i = tid; i < 512; i += 256) {
      *(short8b*)&sAhi[i * 8] = z;
      *(short8b*)&sAlo[i * 8] = z;
    }
  }
  __syncthreads();

  for (int i = tid; i < N; i += 256) {
    const int id = s_ids[i] - kb;
    if ((unsigned)id < (unsigned)KQ) atomicAdd(&s_cnt[id], 1);
  }
  __syncthreads();

  // wave-0 inclusive scan over KQ=25 counts (shfl_up, no block barriers)
  if (tid < 64) {
    const int cv = (tid < KQ) ? s_cnt[tid] : 0;
    int c = cv;
#pragma unroll
    for (int off = 1; off < 32; off <<= 1) {
      const int t = __shfl_up(c, off);
      if (tid >= off) c += t;
    }
    if (tid < KQ) s_off[tid] = c - cv;   // exclusive
    if (tid == KQ - 1) s_off[KQ] = c;
  }
  __syncthreads();

  for (int i = tid; i < N; i += 256) {
    const int id = s_ids[i] - kb;
    if ((unsigned)id < (unsigned)KQ) {
      const int pos = atomicAdd(&s_cur[id], 1);
      s_sorted[s_off[id] + pos] = (id << 9) | i;
    }
  }
  __syncthreads();

  // ---- Phase A gather: wave wv owns clusters [(wv*25)>>2, ((wv+1)*25)>>2) ----
  const int wv = tid >> 6, l = tid & 63;
  {
    const int kl0 = (wv * KQ) >> 2;
    const int kl1 = ((wv + 1) * KQ) >> 2;
    const float* xg = x + (size_t)g * N * D + l * 2;
    // frag-position constants for this lane's k-pair (k0 = 2l, k0+1)
    const int k0 = 2 * l;
    const int ksL = k0 >> 4, kqL = (k0 >> 3) & 1, i0 = k0 & 7;

#define PL_FLUSH(KL, AX, AY, INV)                                          \
    {                                                                      \
      const int blk = ksL * 64 + ((kqL * 32 + (KL)) ^ ksL);                \
      const float fx = (AX) * (INV), fy = (AY) * (INV);                    \
      const ushort hx = f2bf(fx), hy = f2bf(fy);                           \
      ushort2 hv; hv.x = hx; hv.y = hy;                                    \
      ushort2 lv;                                                          \
      lv.x = f2bf(fx - bf2f(hx)); lv.y = f2bf(fy - bf2f(hy));              \
      *(ushort2*)&sAhi[blk * 8 + i0] = hv;                                 \
      *(ushort2*)&sAlo[blk * 8 + i0] = lv;                                 \
    }

    if (kl1 > kl0) {
      const int i0g = s_off[kl0], i1g = s_off[kl1];
      if (i1g > i0g) {
        int prev = -1;
        float ax = 0.0f, ay = 0.0f;
        int pkA[8], pkB[8];
        float2 vA[8], vB[8];

#define PL_LOAD(PK, VV, BASE)                                              \
        {                                                                  \
          _Pragma("unroll")                                                \
          for (int j = 0; j < 8; ++j) {                                    \
            const int mi = ((BASE) + j < i1g) ? (BASE) + j : i1g - 1;      \
            PK[j] = s_sorted[mi];                                          \
          }                                                                \
          _Pragma("unroll")                                                \
          for (int j = 0; j < 8; ++j)                                      \
            VV[j] = *(const float2*)&xg[(size_t)(PK[j] & 511) * D];        \
        }

#define PL_PROC(PK, VV, BASE)                                              \
        {                                                                  \
          _Pragma("unroll")                                                \
          for (int j = 0; j < 8; ++j) {                                    \
            if ((BASE) + j < i1g) {                                        \
              const int id = PK[j] >> 9;                                   \
              if (id != prev) {                                            \
                if (prev >= 0) {                                           \
                  const float inv = 1.0f / (float)s_cnt[prev];             \
                  PL_FLUSH(prev, ax, ay, inv);                             \
                }                                                          \
                ax = VV[j].x; ay = VV[j].y; prev = id;                     \
              } else { ax += VV[j].x; ay += VV[j].y; }                     \
            }                                                              \
          }                                                                \
        }

        int base = i0g;
        PL_LOAD(pkA, vA, base);
        while (base < i1g) {
          if (base + 8 < i1g) PL_LOAD(pkB, vB, base + 8);
          PL_PROC(pkA, vA, base);
          base += 8;
          if (base >= i1g) break;
          if (base + 8 < i1g) PL_LOAD(pkA, vA, base + 8);
          PL_PROC(pkB, vB, base);
          base += 8;
        }
        if (prev >= 0) {
          const float inv = 1.0f / (float)s_cnt[prev];
          PL_FLUSH(prev, ax, ay, inv);
        }
#undef PL_LOAD
#undef PL_PROC
      }
    }
#undef PL_FLUSH
  }
  __syncthreads();

  // ---- Phase B: split-bf16 MFMA, wave wv owns n-tile [wv*32, wv*32+32) ----
  floatx16 acc0;
#pragma unroll
  for (int e = 0; e < 16; ++e) acc0[e] = 0.0f;

  const ushort* whw = wh + (size_t)(wv * 8) * 64 * 8;
  const ushort* wlw = wl + (size_t)(wv * 8) * 64 * 8;

#pragma unroll 2
  for (int ks = 0; ks < 8; ++ks) {
    const int lx = l ^ ks;  // read-side of the write swizzle
    const short8b bh = *(const short8b*)&whw[(ks * 64 + l) * 8];
    const short8b bl = *(const short8b*)&wlw[(ks * 64 + l) * 8];
    const short8b ah = *(const short8b*)&sAhi[(ks * 64 + lx) * 8];
    const short8b al = *(const short8b*)&sAlo[(ks * 64 + lx) * 8];
    acc0 = __builtin_amdgcn_mfma_f32_32x32x16_bf16(ah, bh, acc0, 0, 0, 0);
    acc0 = __builtin_amdgcn_mfma_f32_32x32x16_bf16(ah, bl, acc0, 0, 0, 0);
    acc0 = __builtin_amdgcn_mfma_f32_32x32x16_bf16(al, bh, acc0, 0, 0, 0);
  }

  // epilogue: C/D layout col=lane&31, row=(e&3)+8*(e>>2)+4*(lane>>5)
  const int col = l & 31;
  const int n = wv * 32 + col;
  const float bias = b1[n];
  const int rbase = 4 * (l >> 5);
  float* hrow = h1 + ((size_t)g * K + kb) * D + n;
#pragma unroll
  for (int e = 0; e < 16; ++e) {
    const int row = (e & 3) + 8 * (e >> 2) + rbase;
    if (row < KQ) hrow[(size_t)row * D] = relu(acc0[e] + bias);
  }
}

// ---------------- K3: GEMM2 partials (32-row g-blocks) ----------------
__global__ __launch_bounds__(256) void gemm2_partial(
    const float* __restrict__ h1, const float* __restrict__ W2,
    float* __restrict__ partials) {
  extern __shared__ float smem[];
  float* sHt = smem;             // [32][SH]
  float* sWT = smem + 32 * SH;   // [128][SW2]
  const int kc = blockIdx.x;     // 0..199
  const int gb = blockIdx.y;     // 0..15
  const int k0 = kc * 128, g0 = gb * 32;
  const int tid = threadIdx.x;

  for (int i = tid; i < 32 * 128; i += 256) {
    const int r = i >> 7, k = i & 127;
    sHt[r * SH + k] = h1[(size_t)(g0 + r) * KD + k0 + k];
  }
  for (int i = tid; i < 32 * 128; i += 256) {
    const int j = i >> 7, k = i & 127;
    sWT[k * SW2 + j] = W2[(size_t)j * KD + k0 + k];
  }
  __syncthreads();

  const int jt = tid & 7;   // j block of 4
  const int gt = tid >> 3;  // one g row each (32)
  float acc[4];
#pragma unroll
  for (int j = 0; j < 4; j++) acc[j] = 0.0f;

  for (int k = 0; k < 128; ++k) {
    const float h = sHt[gt * SH + k];
    const float4 w0 = *(const float4*)&sWT[k * SW2 + jt * 4];
    acc[0] = fmaf(h, w0.x, acc[0]); acc[1] = fmaf(h, w0.y, acc[1]);
    acc[2] = fmaf(h, w0.z, acc[2]); acc[3] = fmaf(h, w0.w, acc[3]);
  }

  float* pp = partials + ((size_t)kc * G + g0 + gt) * DMID + jt * 4;
  *(float4*)&pp[0] = make_float4(acc[0], acc[1], acc[2], acc[3]);
}

// ---------------- K4: fused reduce (200 -> h2), grid 256 x 256 ----------------
// Block b owns 64 consecutive idx of the G*DMID space; waves split the 200
// c-chunks 4 ways (50 each), LDS-combine, then +b2, relu. Replaces the old
// two-stage tree (reduce1+reduce2): same read volume (13 MB), one less launch,
// no partials2 round-trip.
__global__ __launch_bounds__(256) void gemm2_reduce(
    const float* __restrict__ partials, const float* __restrict__ b2,
    float* __restrict__ h2) {
  __shared__ float s_red[3][64];
  const int tid = threadIdx.x;
  const int li = tid & 63;   // idx offset within block
  const int w = tid >> 6;    // c-chunk 0..3
  const int idx = blockIdx.x * 64 + li;
  float s = 0.0f;
#pragma unroll 5
  for (int c = w * 50; c < w * 50 + 50; ++c)
    s += partials[(size_t)c * (G * DMID) + idx];
  if (w > 0) s_red[w - 1][li] = s;
  __syncthreads();
  if (w == 0) {
    s += s_red[0][li] + s_red[1][li] + s_red[2][li];
    h2[idx] = relu(s + b2[idx & 31]);
  }
}

// ---------------- K5: GEMM3 + cosine + per-pair squared error ----------------
__global__ __launch_bounds__(256) void head_kernel(
    const float* __restrict__ h2, const float* __restrict__ W3,
    const float* __restrict__ b3, const float* __restrict__ ts,
    float* __restrict__ pair_sq) {
  __shared__ float sA[DMID], sB[DMID];
  __shared__ float rdot[4], rna[4], rnb[4];
  const int p = blockIdx.x;
  const int tid = threadIdx.x;
  if (tid < DMID) sA[tid] = h2[(size_t)(2 * p) * DMID + tid];
  else if (tid < 2 * DMID) sB[tid - DMID] = h2[(size_t)(2 * p + 1) * DMID + (tid - DMID)];
  __syncthreads();

  float dot = 0.0f, na = 0.0f, nb = 0.0f;
#pragma unroll
  for (int rep = 0; rep < 2; ++rep) {
    const int o = rep * 256 + tid;
    const float* w = W3 + (size_t)o * DMID;
    float accA = b3[o], accB = accA;
#pragma unroll
    for (int m = 0; m < DMID; m += 4) {
      const float4 wv = *(const float4*)&w[m];
      accA = fmaf(sA[m], wv.x, accA); accB = fmaf(sB[m], wv.x, accB);
      accA = fmaf(sA[m + 1], wv.y, accA); accB = fmaf(sB[m + 1], wv.y, accB);
      accA = fmaf(sA[m + 2], wv.z, accA); accB = fmaf(sB[m + 2], wv.z, accB);
      accA = fmaf(sA[m + 3], wv.w, accA); accB = fmaf(sB[m + 3], wv.w, accB);
    }
    const float a = relu(accA), b = relu(accB);
    dot = fmaf(a, b, dot); na = fmaf(a, a, na); nb = fmaf(b, b, nb);
  }
#pragma unroll
  for (int off = 32; off >= 1; off >>= 1) {
    dot += __shfl_down(dot, off);
    na  += __shfl_down(na, off);
    nb  += __shfl_down(nb, off);
  }
  const int wave = tid >> 6, lane = tid & 63;
  if (lane == 0) { rdot[wave] = dot; rna[wave] = na; rnb[wave] = nb; }
  __syncthreads();
  if (tid == 0) {
    const float dt = rdot[0] + rdot[1] + rdot[2] + rdot[3];
    const float nA = rna[0] + rna[1] + rna[2] + rna[3];
    const float nB = rnb[0] + rnb[1] + rnb[2] + rnb[3];
    const float n1 = fmaxf(sqrtf(nA), 1e-6f);
    const float n2 = fmaxf(sqrtf(nB), 1e-6f);
    const float sc = dt / (n1 * n2);
    const float e = sc - ts[p];
    pair_sq[p] = e * e;
  }
}

// ---------------- K6: final mean ----------------
__global__ __launch_bounds__(256) void loss_kernel(
    const float* __restrict__ pair_sq, float* __restrict__ out) {
  __shared__ float red[4];
  const int tid = threadIdx.x;
  float v = pair_sq[tid];
#pragma unroll
  for (int off = 32; off >= 1; off >>= 1) v += __shfl_down(v, off);
  const int wave = tid >> 6, lane = tid & 63;
  if (lane == 0) red[wave] = v;
  __syncthreads();
  if (tid == 0) out[0] = (red[0] + red[1] + red[2] + red[3]) * (1.0f / 256.0f);
}

extern "C" void kernel_launch(void* const* d_in, const int* in_sizes, int n_in,
                              void* d_out, int out_size, void* d_ws, size_t ws_size,
                              hipStream_t stream) {
  const float* x       = (const float*)d_in[0];
  const int*   cluster = (const int*)d_in[1];
  const float* ts      = (const float*)d_in[2];
  const float* W1      = (const float*)d_in[3];
  const float* b1      = (const float*)d_in[4];
  const float* W2      = (const float*)d_in[5];
  const float* b2      = (const float*)d_in[6];
  const float* W3      = (const float*)d_in[7];
  const float* b3      = (const float*)d_in[8];

  float* ws = (float*)d_ws;
  float* h1        = ws;                                   // GK*D
  float* partials  = h1 + (size_t)GK * D;                  // NCHUNK*G*DMID
  float* h2        = partials + (size_t)NCHUNK * G * DMID; // G*DMID
  float* pair_sq   = h2 + (size_t)G * DMID;                // 256
  ushort* wfrag_hi = (ushort*)(pair_sq + 256);             // 16384 bf16
  ushort* wfrag_lo = wfrag_hi + 16384;                     // 16384 bf16

  w1prep<<<16384 / 256, 256, 0, stream>>>(W1, wfrag_hi, wfrag_lo);
  dim3 gridP(8, G);
  pool_gemm1_fused<<<gridP, 256, 0, stream>>>(x, cluster, wfrag_hi, wfrag_lo, b1, h1);
  dim3 gridC(NCHUNK, 16);
  gemm2_partial<<<gridC, 256, (32 * SH + 128 * SW2) * sizeof(float), stream>>>(h1, W2, partials);
  gemm2_reduce<<<G * DMID / 64, 256, 0, stream>>>(partials, b2, h2);
  head_kernel<<<G / 2, 256, 0, stream>>>(h2, W3, b3, ts, pair_sq);
  loss_kernel<<<1, 256, 0, stream>>>(pair_sq, (float*)d_out);
}